// Round 7
// baseline (299.585 us; speedup 1.0000x reference)
//
#include <hip/hip_runtime.h>

// GCN block: h1 = ReLU(Agg(x@W1)+b1); h2 = ReLU(Agg(h1@W2)+b2); out = BN(h2)
// R22: L2-resident quartered gathers. R18(+)/R20(0)/R21(0) established the
// agg wall is per-CU outstanding-miss capacity x latency (model T =
// E*4lines*250ns/(52*256CU) = 45us = observed). Fix latency: store gather
// sources as 4 feature-slices of 64B/row (3.2MB each -> fits 4MB per-XCD
// L2). Each agg kernel runs 4 internal phases (one slice each); grid sized
// to exact residency so phases stay coherent; bucket loads + output stores
// are non-temporal so the hot slice survives in L2.
// Group-per-node layout: each 4-lane group owns one node; instruction k
// gathers slot k of 16 nodes -> no cross-lane reduce, slots arrive as int4.
// Self-loop = just another slot (rows are pre-scaled by rsqrt(deg)).
// agg1+GEMM2 un-fused (k_gemm2 standalone) to keep agg kernels lean.

#define D 128
#define CAP 96   // max in-degree capacity (multiple of 16)

typedef __attribute__((ext_vector_type(8))) short bf16x8;
typedef __attribute__((ext_vector_type(4))) float f32x4;
typedef __attribute__((ext_vector_type(8))) float f32x8;
typedef __attribute__((ext_vector_type(4))) unsigned u32x4;
typedef __attribute__((ext_vector_type(4))) int i32x4;

__device__ inline float2 bf2x2(unsigned u) {
    float2 r;
    r.x = __uint_as_float(u << 16);
    r.y = __uint_as_float(u & 0xffff0000u);
    return r;
}
__device__ inline unsigned short f2bf(float f) {
    unsigned u = __float_as_uint(f);
    u += 0x7fffu + ((u >> 16) & 1u);   // round-to-nearest-even
    return (unsigned short)(u >> 16);
}
__device__ inline unsigned pack2(float a, float b) {
    return (unsigned)f2bf(a) | ((unsigned)f2bf(b) << 16);
}

// ------- fused histogram+fill (sequential slots) + W transpose + zero rows -----
__global__ void k_histfill(const int* __restrict__ row, const int* __restrict__ col,
                           int* __restrict__ cnt, int* __restrict__ bucket, int E,
                           const float* __restrict__ W1, const float* __restrict__ W2,
                           unsigned short* __restrict__ Wt1,
                           unsigned short* __restrict__ Wt2,
                           unsigned* __restrict__ hsb_u, unsigned* __restrict__ g2b_u,
                           int N) {
    int e = blockIdx.x * blockDim.x + threadIdx.x;
    if (e < E) {
        int c = col[e];
        int slot = atomicAdd(&cnt[c], 1);
        if (slot < CAP) bucket[(size_t)c * CAP + slot] = row[e];
    }
    if (blockIdx.x < D) {
        int k = blockIdx.x;
        int t = threadIdx.x;
        if (t < D) Wt1[t * D + k] = f2bf(W1[k * D + t]);
        else       Wt2[(t - D) * D + k] = f2bf(W2[k * D + (t - D)]);
    } else if (blockIdx.x == D && threadIdx.x < 128) {
        // zero the sentinel row (row N) of each of the 4 slices of hsb and g2b
        int t = threadIdx.x;
        int which = t >> 4, idx = t & 15;
        size_t selem_u = (size_t)(N + 1) * 16;   // uints per slice
        unsigned* bp = (which < 4 ? hsb_u : g2b_u)
                       + (size_t)(which & 3) * selem_u + (size_t)N * 16;
        bp[idx] = 0u;
    }
}

// ------ 16-wave GEMM compute; epilogue writes QUARTERED prescaled slices ------
__device__ inline void gemm_compute16(const unsigned short* Xs, const unsigned short* Ws,
                                      const int* __restrict__ cnt,
                                      unsigned short* __restrict__ out, size_t selem,
                                      int n, int row0) {
    int tid = threadIdx.x;
    int w = tid >> 6;          // 0..15
    int wm = w >> 1;           // m-tile 0..7
    int wn = w & 1;            // n-half 0..1
    int lane = tid & 63;
    int m16 = lane & 15;
    int quad = lane >> 4;

    f32x4 acc[4];
#pragma unroll
    for (int u = 0; u < 4; u++) acc[u] = (f32x4){0.f, 0.f, 0.f, 0.f};

#pragma unroll
    for (int kc = 0; kc < 4; kc++) {
        bf16x8 a = *(const bf16x8*)&Xs[(wm * 16 + m16) * 136 + kc * 32 + quad * 8];
        bf16x8 b[4];
#pragma unroll
        for (int u = 0; u < 4; u++)
            b[u] = *(const bf16x8*)&Ws[((wn * 4 + u) * 16 + m16) * 136 + kc * 32 + quad * 8];
#pragma unroll
        for (int u = 0; u < 4; u++)
            acc[u] = __builtin_amdgcn_mfma_f32_16x16x32_bf16(a, b[u], acc[u], 0, 0, 0);
    }

    int rbase = row0 + wm * 16 + quad * 4;
#pragma unroll
    for (int i = 0; i < 4; i++) {
        int r = rbase + i;
        if (r < n) {
            float sc = rsqrtf((float)cnt[r] + 1.0f);
#pragma unroll
            for (int u = 0; u < 4; u++) {
                int f = (wn * 4 + u) * 16 + m16;
                int q = f >> 5, fo = f & 31;
                out[(size_t)q * selem + (size_t)r * 32 + fo] = f2bf(acc[u][i] * sc);
            }
        }
    }
}

// -- GEMM1: quartered prescaled hsb = quarter-slices of (X@W1)*rsqrt(cnt+1) --
// Also pads the bucket: self slot at L, 31 sentinels after (covers [T,32) and
// [T, P16) for the tail region).
__global__ __launch_bounds__(1024) void k_gemm1(
        const float* __restrict__ Xf, const unsigned short* __restrict__ Wt,
        const int* __restrict__ cnt, int* __restrict__ bucket,
        unsigned short* __restrict__ out, size_t selem, int n) {
    __shared__ unsigned short Xs[128 * 136];
    __shared__ unsigned short Ws[128 * 136];
    int tid = threadIdx.x;
    int row0 = blockIdx.x * 128;

#pragma unroll
    for (int i = 0; i < 2; i++) {
        int c = tid + 1024 * i;
        int r = c >> 4;
        int kc = (c & 15) * 8;
        float4 va = {0.f, 0.f, 0.f, 0.f}, vb = {0.f, 0.f, 0.f, 0.f};
        if (row0 + r < n) {
            va = *(const float4*)&Xf[(size_t)(row0 + r) * D + kc];
            vb = *(const float4*)&Xf[(size_t)(row0 + r) * D + kc + 4];
        }
        ushort4 o0, o1;
        o0.x = f2bf(va.x); o0.y = f2bf(va.y); o0.z = f2bf(va.z); o0.w = f2bf(va.w);
        o1.x = f2bf(vb.x); o1.y = f2bf(vb.y); o1.z = f2bf(vb.z); o1.w = f2bf(vb.w);
        *(ushort4*)&Xs[r * 136 + kc] = o0;
        *(ushort4*)&Xs[r * 136 + kc + 4] = o1;
    }
#pragma unroll
    for (int i = 0; i < 2; i++) {
        int c = tid + 1024 * i;
        int r = c >> 4;
        int kc = (c & 15) * 8;
        uint4 v = *(const uint4*)&Wt[r * D + kc];
        *(uint4*)&Ws[r * 136 + kc] = v;
    }
    // bucket pad: 8 threads per node; self at L, sentinels L+1..L+31 (<CAP)
    {
        int nl = tid >> 3;
        int node = row0 + nl;
        if (node < n) {
            int L = min(cnt[node], CAP - 1);
            int* bp = bucket + (size_t)node * CAP;
            if ((tid & 7) == 0) bp[L] = node;           // self slot
#pragma unroll
            for (int i = (tid & 7); i < 31; i += 8) {
                int p = L + 1 + i;
                if (p < CAP) bp[p] = n;                  // sentinel -> zero row
            }
        }
    }
    __syncthreads();
    gemm_compute16(Xs, Ws, cnt, out, selem, n, row0);
}

// -------- GEMM2: bf16 input a1b -> quartered prescaled g2b --------
__global__ __launch_bounds__(1024) void k_gemm2(
        const unsigned short* __restrict__ A, const unsigned short* __restrict__ Wt,
        const int* __restrict__ cnt, unsigned short* __restrict__ out,
        size_t selem, int n) {
    __shared__ unsigned short Xs[128 * 136];
    __shared__ unsigned short Ws[128 * 136];
    int tid = threadIdx.x;
    int row0 = blockIdx.x * 128;
#pragma unroll
    for (int i = 0; i < 2; i++) {
        int c = tid + 1024 * i;
        int r = c >> 4;
        int kc = (c & 15) * 8;
        uint4 v = {0u, 0u, 0u, 0u};
        if (row0 + r < n) v = *(const uint4*)&A[(size_t)(row0 + r) * D + kc];
        *(uint4*)&Xs[r * 136 + kc] = v;
    }
#pragma unroll
    for (int i = 0; i < 2; i++) {
        int c = tid + 1024 * i;
        int r = c >> 4;
        int kc = (c & 15) * 8;
        uint4 v = *(const uint4*)&Wt[r * D + kc];
        *(uint4*)&Ws[r * 136 + kc] = v;
    }
    __syncthreads();
    gemm_compute16(Xs, Ws, cnt, out, selem, n, row0);
}

// ---- forced-MLP gather: 8 concurrent 64B-slot gathers (16 nodes/instr·slot) ----
struct G8Q { u32x4 a, b, c, d, e, f, g, h; };

__device__ inline G8Q issue8q(const char* base,
                              unsigned o0, unsigned o1, unsigned o2, unsigned o3,
                              unsigned o4, unsigned o5, unsigned o6, unsigned o7) {
    G8Q r;
    asm volatile(
        "global_load_dwordx4 %0, %8, %16\n\t"
        "global_load_dwordx4 %1, %9, %16\n\t"
        "global_load_dwordx4 %2, %10, %16\n\t"
        "global_load_dwordx4 %3, %11, %16\n\t"
        "global_load_dwordx4 %4, %12, %16\n\t"
        "global_load_dwordx4 %5, %13, %16\n\t"
        "global_load_dwordx4 %6, %14, %16\n\t"
        "global_load_dwordx4 %7, %15, %16"
        : "=&v"(r.a), "=&v"(r.b), "=&v"(r.c), "=&v"(r.d),
          "=&v"(r.e), "=&v"(r.f), "=&v"(r.g), "=&v"(r.h)
        : "v"(o0), "v"(o1), "v"(o2), "v"(o3),
          "v"(o4), "v"(o5), "v"(o6), "v"(o7),
          "s"(base));
    return r;
}

__device__ inline void wait_vm0() {
    asm volatile("s_waitcnt vmcnt(0)" ::: "memory");
    __builtin_amdgcn_sched_barrier(0);   // keep consumers below the wait
}

__device__ inline void cons4(const u32x4& u, f32x8& A) {
    float2 x;
    x = bf2x2(u[0]); A[0] += x.x; A[1] += x.y;
    x = bf2x2(u[1]); A[2] += x.x; A[3] += x.y;
    x = bf2x2(u[2]); A[4] += x.x; A[5] += x.y;
    x = bf2x2(u[3]); A[6] += x.x; A[7] += x.y;
}
__device__ inline void consume8q(const G8Q& g, f32x8& A) {
    cons4(g.a, A); cons4(g.b, A); cons4(g.c, A); cons4(g.d, A);
    cons4(g.e, A); cons4(g.f, A); cons4(g.g, A); cons4(g.h, A);
}

#define QOFF(s) ((((unsigned)(s)) << 6) + l4b)

// ---- per-wave: aggregate one group of 16 nodes for slice q into A[8]/lane ----
// Lane l owns node n0+(l>>2), features (l&3)*8..+8 of the quarter.
__device__ inline void agg16(const char* sq, const int* __restrict__ bucket,
                             int node, int nvalid, int dc, int N,
                             unsigned l4b, f32x8& A) {
    const int* bp = bucket + (size_t)min(node, N - 1) * CAP;
    A = (f32x8){0.f, 0.f, 0.f, 0.f, 0.f, 0.f, 0.f, 0.f};
#pragma unroll
    for (int kb = 0; kb < 4; kb++) {          // slots kb*8 .. kb*8+7
        i32x4 sa = __builtin_nontemporal_load((const i32x4*)(bp + kb * 8));
        i32x4 sb = __builtin_nontemporal_load((const i32x4*)(bp + kb * 8 + 4));
        if (!nvalid) { sa = (i32x4){N, N, N, N}; sb = sa; }
        G8Q g = issue8q(sq, QOFF(sa[0]), QOFF(sa[1]), QOFF(sa[2]), QOFF(sa[3]),
                            QOFF(sb[0]), QOFF(sb[1]), QOFF(sb[2]), QOFF(sb[3]));
        wait_vm0();
        consume8q(g, A);
    }
    // rare tail: dc >= 32 (slots 32..P16)
    int L = min(dc, CAP - 1);
    int P16 = ((L + 16) >> 4) << 4;           // ceil((L+1)/16)*16
    if (!nvalid) P16 = 0;
    if (__builtin_expect(__any(P16 > 32), 0)) {
#pragma unroll 1
        for (int k = 32; k < CAP; k += 8) {
            if (!__any(P16 > k)) break;
            i32x4 sa = __builtin_nontemporal_load((const i32x4*)(bp + k));
            i32x4 sb = __builtin_nontemporal_load((const i32x4*)(bp + k + 4));
#pragma unroll
            for (int i = 0; i < 4; i++) {
                if (k + i >= P16) sa[i] = N;
                if (k + 4 + i >= P16) sb[i] = N;
            }
            G8Q g = issue8q(sq, QOFF(sa[0]), QOFF(sa[1]), QOFF(sa[2]), QOFF(sa[3]),
                                QOFF(sb[0]), QOFF(sb[1]), QOFF(sb[2]), QOFF(sb[3]));
            wait_vm0();
            consume8q(g, A);
        }
    }
}

// ---------------- agg1: 4 slice-phases, writes a1b (standard layout) ----------------
__global__ __launch_bounds__(512) void k_agg1(
        const char* __restrict__ src, const int* __restrict__ bucket,
        const int* __restrict__ cnt, const float* __restrict__ bias,
        unsigned short* __restrict__ outp, size_t selem, int N) {
    int tid = threadIdx.x;
    int w = tid >> 6;
    int lane = tid & 63;
    int grp4 = lane >> 2, l4 = lane & 3;
    unsigned l4b = (unsigned)l4 * 16u;
    int gw = blockIdx.x * 8 + w, nw = gridDim.x * 8;
    int ngroups = (N + 15) >> 4;

#pragma unroll 1
    for (int q = 0; q < 4; q++) {
        const char* sq = src + (size_t)q * selem * 2;
        float4 ba = *(const float4*)&bias[q * 32 + l4 * 8];
        float4 bb = *(const float4*)&bias[q * 32 + l4 * 8 + 4];
#pragma unroll 1
        for (int gi = gw; gi < ngroups; gi += nw) {
            int node = gi * 16 + grp4;
            int nvalid = node < N;
            int dc = cnt[min(node, N - 1)];
            f32x8 A;
            agg16(sq, bucket, node, nvalid, dc, N, l4b, A);
            if (nvalid) {
                float dn = rsqrtf((float)dc + 1.0f);
                u32x4 o;
                o[0] = pack2(fmaxf(dn * A[0] + ba.x, 0.f), fmaxf(dn * A[1] + ba.y, 0.f));
                o[1] = pack2(fmaxf(dn * A[2] + ba.z, 0.f), fmaxf(dn * A[3] + ba.w, 0.f));
                o[2] = pack2(fmaxf(dn * A[4] + bb.x, 0.f), fmaxf(dn * A[5] + bb.y, 0.f));
                o[3] = pack2(fmaxf(dn * A[6] + bb.z, 0.f), fmaxf(dn * A[7] + bb.w, 0.f));
                __builtin_nontemporal_store(
                    o, (u32x4*)&outp[(size_t)node * D + q * 32 + l4 * 8]);
            }
        }
        __syncthreads();   // keep the block phase-coherent for L2 locality
    }
}

// ------- agg2 + BN-stats: 4 slice-phases, writes h2b (standard) + S -------
__global__ __launch_bounds__(512) void k_agg2s(
        const char* __restrict__ src, const int* __restrict__ bucket,
        const int* __restrict__ cnt, const float* __restrict__ bias,
        unsigned short* __restrict__ h2, float* __restrict__ S,
        size_t selem, int N) {
    int tid = threadIdx.x;
    int w = tid >> 6;
    int lane = tid & 63;
    int grp4 = lane >> 2, l4 = lane & 3;
    unsigned l4b = (unsigned)l4 * 16u;
    int gw = blockIdx.x * 8 + w, nw = gridDim.x * 8;
    int ngroups = (N + 15) >> 4;

    __shared__ float sm[8][128][2];

#pragma unroll 1
    for (int q = 0; q < 4; q++) {
        const char* sq = src + (size_t)q * selem * 2;
        float4 ba = *(const float4*)&bias[q * 32 + l4 * 8];
        float4 bb = *(const float4*)&bias[q * 32 + l4 * 8 + 4];
        f32x8 st = {0.f, 0.f, 0.f, 0.f, 0.f, 0.f, 0.f, 0.f};
        f32x8 sq_ = {0.f, 0.f, 0.f, 0.f, 0.f, 0.f, 0.f, 0.f};
#pragma unroll 1
        for (int gi = gw; gi < ngroups; gi += nw) {
            int node = gi * 16 + grp4;
            int nvalid = node < N;
            int dc = cnt[min(node, N - 1)];
            f32x8 A;
            agg16(sq, bucket, node, nvalid, dc, N, l4b, A);
            if (nvalid) {
                float dn = rsqrtf((float)dc + 1.0f);
                float v0 = fmaxf(dn * A[0] + ba.x, 0.f);
                float v1 = fmaxf(dn * A[1] + ba.y, 0.f);
                float v2 = fmaxf(dn * A[2] + ba.z, 0.f);
                float v3 = fmaxf(dn * A[3] + ba.w, 0.f);
                float v4 = fmaxf(dn * A[4] + bb.x, 0.f);
                float v5 = fmaxf(dn * A[5] + bb.y, 0.f);
                float v6 = fmaxf(dn * A[6] + bb.z, 0.f);
                float v7 = fmaxf(dn * A[7] + bb.w, 0.f);
                u32x4 o;
                o[0] = pack2(v0, v1); o[1] = pack2(v2, v3);
                o[2] = pack2(v4, v5); o[3] = pack2(v6, v7);
                __builtin_nontemporal_store(
                    o, (u32x4*)&h2[(size_t)node * D + q * 32 + l4 * 8]);
                st[0] += v0; st[1] += v1; st[2] += v2; st[3] += v3;
                st[4] += v4; st[5] += v5; st[6] += v6; st[7] += v7;
                sq_[0] += v0 * v0; sq_[1] += v1 * v1; sq_[2] += v2 * v2;
                sq_[3] += v3 * v3; sq_[4] += v4 * v4; sq_[5] += v5 * v5;
                sq_[6] += v6 * v6; sq_[7] += v7 * v7;
            }
        }
        // reduce the 16 same-feature lanes (groups span lane bits 2..5)
#pragma unroll
        for (int j = 0; j < 8; j++) {
            float s = st[j], t = sq_[j];
            s += __shfl_xor(s, 4);  t += __shfl_xor(t, 4);
            s += __shfl_xor(s, 8);  t += __shfl_xor(t, 8);
            s += __shfl_xor(s, 16); t += __shfl_xor(t, 16);
            s += __shfl_xor(s, 32); t += __shfl_xor(t, 32);
            if (grp4 == 0) {
                sm[w][q * 32 + l4 * 8 + j][0] = s;
                sm[w][q * 32 + l4 * 8 + j][1] = t;
            }
        }
        __syncthreads();
    }
    if (tid < D) {
        float s = 0.f, t = 0.f;
#pragma unroll
        for (int ww = 0; ww < 8; ww++) {
            s += sm[ww][tid][0];
            t += sm[ww][tid][1];
        }
        atomicAdd(&S[tid * 16], s);
        atomicAdd(&S[4096 + tid * 16], t);
    }
}

// ---------------- BN normalize: bf16 h2 -> f32 out ----------------
__global__ void k_bn(const unsigned* __restrict__ z2, const float* __restrict__ S,
                     const float* __restrict__ gamma, const float* __restrict__ beta,
                     float* __restrict__ out, int N) {
    int i = blockIdx.x * blockDim.x + threadIdx.x;   // uint4 index (8 features)
    int total = N * (D / 8);
    if (i >= total) return;
    int c8 = (i & (D / 8 - 1)) * 8;
    uint4 u = *(const uint4*)&z2[(size_t)i * 4];
    float v[8];
    float2 t;
    t = bf2x2(u.x); v[0] = t.x; v[1] = t.y;
    t = bf2x2(u.y); v[2] = t.x; v[3] = t.y;
    t = bf2x2(u.z); v[4] = t.x; v[5] = t.y;
    t = bf2x2(u.w); v[6] = t.x; v[7] = t.y;
    float invN = 1.0f / (float)N;
    float4 o0, o1;
#pragma unroll
    for (int j = 0; j < 8; j++) {
        float s = S[(c8 + j) * 16];
        float s2 = S[4096 + (c8 + j) * 16];
        float mu = s * invN;
        float iv = rsqrtf(fmaxf(s2 * invN - mu * mu, 0.f) + 1e-5f);
        float val = gamma[c8 + j] * (v[j] - mu) * iv + beta[c8 + j];
        if (j < 4) (&o0.x)[j] = val; else (&o1.x)[j - 4] = val;
    }
    size_t base = (size_t)i * 8;
    *(float4*)&out[base] = o0;
    *(float4*)&out[base + 4] = o1;
}

static inline size_t align_up(size_t x) { return (x + 1023) & ~(size_t)1023; }

extern "C" void kernel_launch(void* const* d_in, const int* in_sizes, int n_in,
                              void* d_out, int out_size, void* d_ws, size_t ws_size,
                              hipStream_t stream) {
    const float* x     = (const float*)d_in[0];
    const int*   ei    = (const int*)d_in[1];
    const float* W1    = (const float*)d_in[2];
    const float* b1    = (const float*)d_in[3];
    const float* W2    = (const float*)d_in[4];
    const float* b2    = (const float*)d_in[5];
    const float* gamma = (const float*)d_in[6];
    const float* beta  = (const float*)d_in[7];

    int N = in_sizes[0] / D;
    int E = in_sizes[1] / 2;
    const int* row = ei;
    const int* col = ei + E;

    size_t selem = (size_t)(N + 1) * 32;   // ushorts per feature-quarter slice

    char* p = (char*)d_ws;
    int* cnt    = (int*)p;                 // cnt[N] ++ S[8192]: one memset
    float* S    = (float*)(cnt + N);       // strided sums/sumsq, 32KB
    p += align_up((size_t)(N + 8192) * 4);
    int* bucket = (int*)p;   p += align_up((size_t)N * CAP * 4);
    // hsb/g2b: 4 slices x (N+1) rows x 64B (row N of each slice = zeros)
    unsigned short* hsb = (unsigned short*)p; p += align_up((size_t)(N + 1) * D * 2);
    unsigned short* g2b = (unsigned short*)p; p += align_up((size_t)(N + 1) * D * 2);
    unsigned short* a1b = (unsigned short*)p; p += align_up((size_t)N * D * 2);
    unsigned short* h2b = (unsigned short*)p; p += align_up((size_t)N * D * 2);
    unsigned short* Wt1 = (unsigned short*)p; p += align_up((size_t)D * D * 2);
    unsigned short* Wt2 = (unsigned short*)p; p += align_up((size_t)D * D * 2);

    int gemmBlocks = (N + 127) / 128;            // 391
    int fillBlocks = (E + 255) / 256;            // 2344
    int aggBlocks  = (((N + 15) >> 4) + 7) / 8;  // 391: all-resident grid

    hipMemsetAsync(cnt, 0, (size_t)(N + 8192) * 4, stream);
    k_histfill<<<fillBlocks, 256, 0, stream>>>(row, col, cnt, bucket, E,
                                               W1, W2, Wt1, Wt2,
                                               (unsigned*)hsb, (unsigned*)g2b, N);
    // layer 1 GEMM -> quartered prescaled hsb (+ bucket self/sentinel pad)
    k_gemm1<<<gemmBlocks, 1024, 0, stream>>>(x, Wt1, cnt, bucket, hsb, selem, N);
    // layer 1 aggregation (4 L2-resident slice phases) -> a1b
    k_agg1<<<aggBlocks, 512, 0, stream>>>((const char*)hsb, bucket, cnt, b1,
                                          a1b, selem, N);
    // layer 2 GEMM -> quartered prescaled g2b
    k_gemm2<<<gemmBlocks, 1024, 0, stream>>>(a1b, Wt2, cnt, g2b, selem, N);
    // layer 2 aggregation + BN stats -> h2b, S
    k_agg2s<<<aggBlocks, 512, 0, stream>>>((const char*)g2b, bucket, cnt, b2,
                                           h2b, S, selem, N);
    // BN normalize
    k_bn<<<(N * (D / 8) + 255) / 256, 256, 0, stream>>>((const unsigned*)h2b, S,
                                                        gamma, beta, (float*)d_out, N);
}